// Round 17
// baseline (49.660 us; speedup 1.0000x reference)
//
#include <hip/hip_runtime.h>
#include <hip/hip_bf16.h>

#define DEVI __device__ __forceinline__

typedef short bf16x8 __attribute__((ext_vector_type(8)));
typedef float f32x4 __attribute__((ext_vector_type(4)));
typedef unsigned short u16x4 __attribute__((ext_vector_type(4)));

static constexpr int B_ = 2, N_ = 2048, DIM_ = 256, H_ = 4, DH_ = 32;
static constexpr int NQKV_ = 3 * H_ * DH_;  // 384
static constexpr float SCALE_ = 0.17677669529663687f;  // DH^-0.5

DEVI unsigned short f2bf(float f) {
  __hip_bfloat16 h = __float2bfloat16(f);
  return *reinterpret_cast<unsigned short*>(&h);
}

// --------------------------------------------------------------- qkv gemm ---
// (byte-identical to round 10)
__global__ __launch_bounds__(256) void k_gemm_qkv(
    const float* __restrict__ X,            // x fp32 [4096][256]
    const float* __restrict__ Wqkv,         // fp32 [256][384]
    unsigned short* __restrict__ Qo,        // [B,H,N,DH] pre-scaled
    unsigned short* __restrict__ Ko,        // [B,H,N,DH]
    unsigned short* __restrict__ Vo,        // [B,H,N,DH]
    unsigned short* __restrict__ Vto) {     // [B,H,DH,N] key-permuted
  constexpr int LDB = 258;                  // halves
  __shared__ unsigned short Bts[64 * LDB];  // 32.25 KB
  const int tid = threadIdx.x;
  const int col0b = blockIdx.y * 64;
  for (int p = tid; p < 64 * 256; p += 256) {
    const int col = p & 63;
    const int k = p >> 6;
    Bts[col * LDB + k] = f2bf(Wqkv[k * NQKV_ + col0b + col]);
  }
  __syncthreads();

  const int w = tid >> 6, l = tid & 63;
  const int lr = l & 15, g = l >> 4;
  const int row0 = blockIdx.x * 64 + (w >> 1) * 32;
  const int colw = (w & 1) * 32;
  const float* xr0 = X + (size_t)(row0 + lr) * 256;
  const float* xr1 = X + (size_t)(row0 + 16 + lr) * 256;
  f32x4 acc[2][2] = {};
#pragma unroll
  for (int kb = 0; kb < 256; kb += 32) {
    f32x4 xa = *(const f32x4*)(xr0 + kb + g * 8);
    f32x4 xb4 = *(const f32x4*)(xr0 + kb + g * 8 + 4);
    f32x4 xc = *(const f32x4*)(xr1 + kb + g * 8);
    f32x4 xd = *(const f32x4*)(xr1 + kb + g * 8 + 4);
    bf16x8 a0, a1;
#pragma unroll
    for (int j = 0; j < 4; j++) {
      a0[j] = (short)f2bf(xa[j]);
      a0[4 + j] = (short)f2bf(xb4[j]);
      a1[j] = (short)f2bf(xc[j]);
      a1[4 + j] = (short)f2bf(xd[j]);
    }
    bf16x8 b0 = *(const bf16x8*)(&Bts[(colw + lr) * LDB + kb + g * 8]);
    bf16x8 b1 = *(const bf16x8*)(&Bts[(colw + 16 + lr) * LDB + kb + g * 8]);
    acc[0][0] = __builtin_amdgcn_mfma_f32_16x16x32_bf16(a0, b0, acc[0][0], 0, 0, 0);
    acc[0][1] = __builtin_amdgcn_mfma_f32_16x16x32_bf16(a0, b1, acc[0][1], 0, 0, 0);
    acc[1][0] = __builtin_amdgcn_mfma_f32_16x16x32_bf16(a1, b0, acc[1][0], 0, 0, 0);
    acc[1][1] = __builtin_amdgcn_mfma_f32_16x16x32_bf16(a1, b1, acc[1][1], 0, 0, 0);
  }
#pragma unroll
  for (int mi = 0; mi < 2; mi++)
#pragma unroll
    for (int ni = 0; ni < 2; ni++) {
      const int colg = col0b + colw + ni * 16 + lr;  // 0..383
      const int sec = colg >> 7;                     // 0=Q 1=K 2=V
      const int h = (colg >> 5) & 3;
      const int d = colg & 31;
      const int rbase = row0 + mi * 16 + g * 4;
      const int bb = rbase >> 11;
      const int n0 = rbase & (N_ - 1);
      if (sec == 0) {
#pragma unroll
        for (int r = 0; r < 4; r++)
          Qo[((bb * H_ + h) * N_ + n0 + r) * DH_ + d] = f2bf(acc[mi][ni][r] * SCALE_);
      } else if (sec == 1) {
#pragma unroll
        for (int r = 0; r < 4; r++)
          Ko[((bb * H_ + h) * N_ + n0 + r) * DH_ + d] = f2bf(acc[mi][ni][r]);
      } else {
        u16x4 vp;
#pragma unroll
        for (int r = 0; r < 4; r++) {
          const unsigned short vb = f2bf(acc[mi][ni][r]);
          Vo[((bb * H_ + h) * N_ + n0 + r) * DH_ + d] = vb;
          vp[r] = vb;
        }
        // key-permuted Vt: slot s holds key(s)=4*(s>>3)+(s&3)+16*((s>>2)&1)
        const int c32 = n0 & ~31;
        const int local = n0 & 31;
        const int slot = ((local & 15) >> 2) * 8 + ((local >> 4) << 2);
        *(u16x4*)(Vto + ((bb * H_ + h) * DH_ + d) * N_ + c32 + slot) = vp;
      }
    }
}

// ------------- attention (nsp=2 key split, 6 waves/SIMD, lean body) ---------
// Block = 16 q-rows x 1024 keys (sp half) of one (b,h); 8 waves; wave w owns
// keys sp*1024 + w*128 .. +127 = 4 fully-unrolled 32-key bodies. Direct
// per-lane fp32 bias loads (8 lanes x 16B = one full 128B line per row).
// Zero in-loop barriers, zero staging LDS -> VGPR fits 84 (6 waves/SIMD,
// +50% TLP vs rounds 10-16) and per-wave serial chain is halved.
// Fixed m=0 softmax (scores ~|5|). LDS only for the cross-wave reduce.
// Partials (fp32) go to PO/PS; combined in k_combine.
__global__ __launch_bounds__(512, 6) void k_attn2(
    const unsigned short* __restrict__ Q,
    const unsigned short* __restrict__ K,
    const unsigned short* __restrict__ Vt,
    const float* __restrict__ bias,
    const int* __restrict__ mask,
    float* __restrict__ PO,   // [BH][2][N][32] f32 (unnormalized O partials)
    float* __restrict__ PS) { // [BH][2][N]     f32 (partial sums)
  const int bh = blockIdx.z;
  const int b = bh >> 2, h = bh & 3;
  if (mask[b] != 0) return;   // masked batch handled entirely in k_combine
  const int qt = blockIdx.x, sp = blockIdx.y;
  const int tid = threadIdx.x;
  const int qb = qt * 16;
  __shared__ float so[16][8][32];  // [q][wave][d]  16 KB
  __shared__ float ss[16][8];      // [q][wave]     512 B
  const int w = tid >> 6, l = tid & 63, lr = l & 15, g = l >> 4;
  const int c0 = sp * 1024 + w * 128;  // this wave's 128-key chunk
  const unsigned short* Kp = K + bh * N_ * DH_;
  const unsigned short* Vtp = Vt + bh * DH_ * N_;
  const float* biasrow = bias + (size_t)(h * N_ + qb + lr) * N_;
  const bf16x8 qf = *(const bf16x8*)(Q + (bh * N_ + qb + lr) * DH_ + g * 8);
  float s = 0.f;
  f32x4 o0 = {}, o1 = {};
#pragma unroll
  for (int i = 0; i < 4; i++) {
    const int c = c0 + i * 32;
    bf16x8 k0 = *(const bf16x8*)(Kp + (c + lr) * DH_ + g * 8);
    bf16x8 k1 = *(const bf16x8*)(Kp + (c + 16 + lr) * DH_ + g * 8);
    f32x4 z = {};
    f32x4 st0 = __builtin_amdgcn_mfma_f32_16x16x32_bf16(k0, qf, z, 0, 0, 0);
    f32x4 st1 = __builtin_amdgcn_mfma_f32_16x16x32_bf16(k1, qf, z, 0, 0, 0);
    f32x4 bi0 = *(const f32x4*)(biasrow + c + g * 4);
    f32x4 bi1 = *(const f32x4*)(biasrow + c + 16 + g * 4);
    bf16x8 pf;
#pragma unroll
    for (int r = 0; r < 4; r++) {
      const float p0 = __expf(st0[r] + bi0[r]);
      const float p1 = __expf(st1[r] + bi1[r]);
      s += p0 + p1;
      pf[r] = (short)f2bf(p0);
      pf[4 + r] = (short)f2bf(p1);
    }
    bf16x8 v0 = *(const bf16x8*)(Vtp + lr * N_ + c + g * 8);
    bf16x8 v1 = *(const bf16x8*)(Vtp + (16 + lr) * N_ + c + g * 8);
    o0 = __builtin_amdgcn_mfma_f32_16x16x32_bf16(v0, pf, o0, 0, 0, 0);
    o1 = __builtin_amdgcn_mfma_f32_16x16x32_bf16(v1, pf, o1, 0, 0, 0);
  }
  // per-wave s for q=lr: reduce over the 4 lane-groups
  s += __shfl_xor(s, 16);
  s += __shfl_xor(s, 32);
  *(f32x4*)&so[lr][w][g * 4] = o0;        // d = g*4+r
  *(f32x4*)&so[lr][w][16 + g * 4] = o1;   // d = 16+g*4+r
  if (g == 0) ss[lr][w] = s;
  __syncthreads();
  // cross-wave reduce -> fp32 partials: thread t -> q=t>>5, d=t&31
  {
    const int q = tid >> 5;
    const int d = tid & 31;
    float acc = 0.f, ssum = 0.f;
#pragma unroll
    for (int w2 = 0; w2 < 8; w2++) {
      acc += so[q][w2][d];
      ssum += ss[q][w2];
    }
    PO[((size_t)(bh * 2 + sp) * N_ + qb + q) * 32 + d] = acc;
    if (d == 0) PS[(size_t)(bh * 2 + sp) * N_ + qb + q] = ssum;
  }
}

// ----------------------------------------------------------------- combine ---
// AO[b*N+q][h*32+d] = (PO[sp0]+PO[sp1]) / (PS[sp0]+PS[sp1]) (bf16);
// masked batches: AO = V. One 8-dim unit per thread; 256 blocks x 256 thr.
__global__ __launch_bounds__(256) void k_combine(
    const float* __restrict__ PO, const float* __restrict__ PS,
    const unsigned short* __restrict__ V, const int* __restrict__ mask,
    unsigned short* __restrict__ AO) {
  const int t = blockIdx.x * 256 + threadIdx.x;  // B*H*N*4 = 65536 total
  const int d8 = (t & 3) * 8;
  const int q = (t >> 2) & (N_ - 1);
  const int h = (t >> 13) & (H_ - 1);
  const int b = t >> 15;
  const int bh = b * H_ + h;
  unsigned short* dst = AO + ((size_t)(b * N_ + q)) * (H_ * DH_) + h * DH_ + d8;
  if (mask[b] != 0) {
    bf16x8 v = *(const bf16x8*)(V + ((size_t)bh * N_ + q) * DH_ + d8);
    *(bf16x8*)dst = v;
    return;
  }
  const size_t base0 = (size_t)(bh * 2 + 0) * N_ + q;
  const size_t base1 = (size_t)(bh * 2 + 1) * N_ + q;
  f32x4 a0 = *(const f32x4*)(PO + base0 * 32 + d8);
  f32x4 a0h = *(const f32x4*)(PO + base0 * 32 + d8 + 4);
  f32x4 a1 = *(const f32x4*)(PO + base1 * 32 + d8);
  f32x4 a1h = *(const f32x4*)(PO + base1 * 32 + d8 + 4);
  const float inv = 1.f / (PS[base0] + PS[base1]);
  u16x4 w0, w1;
#pragma unroll
  for (int r = 0; r < 4; r++) {
    w0[r] = f2bf((a0[r] + a1[r]) * inv);
    w1[r] = f2bf((a0h[r] + a1h[r]) * inv);
  }
  *(u16x4*)dst = w0;
  *(u16x4*)(dst + 4) = w1;
}

// --------------------------------------------------------------- out gemm ---
// (byte-identical to round 10)
__global__ __launch_bounds__(256) void k_gemm_out(
    const unsigned short* __restrict__ A,   // AO [4096][128]
    const float* __restrict__ Wout,         // fp32 [128][256]
    float* __restrict__ out) {              // [4096][256] fp32
  constexpr int LDB = 130;                  // halves
  __shared__ unsigned short Bts[64 * LDB];  // 16.25 KB
  const int tid = threadIdx.x;
  const int col0b = blockIdx.y * 64;
  for (int p = tid; p < 64 * 128; p += 256) {
    const int col = p & 63;
    const int k = p >> 6;
    Bts[col * LDB + k] = f2bf(Wout[k * 256 + col0b + col]);
  }
  __syncthreads();

  const int w = tid >> 6, l = tid & 63;
  const int lr = l & 15, g = l >> 4;
  const int row0 = blockIdx.x * 64 + (w >> 1) * 32;
  const int colw = (w & 1) * 32;
  f32x4 acc[2][2] = {};
#pragma unroll
  for (int kb = 0; kb < 128; kb += 32) {
    bf16x8 a0 = *(const bf16x8*)(A + (row0 + lr) * 128 + kb + g * 8);
    bf16x8 a1 = *(const bf16x8*)(A + (row0 + 16 + lr) * 128 + kb + g * 8);
    bf16x8 b0 = *(const bf16x8*)(&Bts[(colw + lr) * LDB + kb + g * 8]);
    bf16x8 b1 = *(const bf16x8*)(&Bts[(colw + 16 + lr) * LDB + kb + g * 8]);
    acc[0][0] = __builtin_amdgcn_mfma_f32_16x16x32_bf16(a0, b0, acc[0][0], 0, 0, 0);
    acc[0][1] = __builtin_amdgcn_mfma_f32_16x16x32_bf16(a0, b1, acc[0][1], 0, 0, 0);
    acc[1][0] = __builtin_amdgcn_mfma_f32_16x16x32_bf16(a1, b0, acc[1][0], 0, 0, 0);
    acc[1][1] = __builtin_amdgcn_mfma_f32_16x16x32_bf16(a1, b1, acc[1][1], 0, 0, 0);
  }
#pragma unroll
  for (int mi = 0; mi < 2; mi++)
#pragma unroll
    for (int ni = 0; ni < 2; ni++) {
      const int colg = col0b + colw + ni * 16 + lr;
      const int rbase = row0 + mi * 16 + g * 4;
#pragma unroll
      for (int r = 0; r < 4; r++)
        out[(size_t)(rbase + r) * 256 + colg] = acc[mi][ni][r];
    }
}

// ------------------------------------------------------------------ launch ---
extern "C" void kernel_launch(void* const* d_in, const int* in_sizes, int n_in,
                              void* d_out, int out_size, void* d_ws, size_t ws_size,
                              hipStream_t stream) {
  const float* x = (const float*)d_in[0];
  const float* bias = (const float*)d_in[1];
  const int* mask = (const int*)d_in[2];
  const float* Wqkv = (const float*)d_in[3];
  const float* Wout = (const float*)d_in[4];
  float* out = (float*)d_out;
  char* ws = (char*)d_ws;

  unsigned short* Qb  = (unsigned short*)(ws + 0);         // 1 MB
  unsigned short* Kb  = (unsigned short*)(ws + 1048576);   // 1 MB
  unsigned short* Vb  = (unsigned short*)(ws + 2097152);   // 1 MB
  unsigned short* Vtb = (unsigned short*)(ws + 3145728);   // 1 MB
  unsigned short* AOb = (unsigned short*)(ws + 4194304);   // 1 MB
  float* PO           = (float*)(ws + 5242880);            // 4 MB
  float* PS           = (float*)(ws + 9437184);            // 128 KB

  k_gemm_qkv<<<dim3(64, 6), dim3(256), 0, stream>>>(x, Wqkv, Qb, Kb, Vb, Vtb);
  k_attn2<<<dim3(128, 2, B_ * H_), dim3(512), 0, stream>>>(
      Qb, Kb, Vtb, bias, mask, PO, PS);
  k_combine<<<dim3(256), dim3(256), 0, stream>>>(PO, PS, Vb, mask, AOb);
  k_gemm_out<<<dim3(64, 4), dim3(256), 0, stream>>>(AOb, Wout, out);
}

// Round 18
// 38.584 us; speedup vs baseline: 1.2871x; 1.2871x over previous
//
#include <hip/hip_runtime.h>
#include <hip/hip_bf16.h>

#define DEVI __device__ __forceinline__

typedef short bf16x8 __attribute__((ext_vector_type(8)));
typedef float f32x4 __attribute__((ext_vector_type(4)));
typedef unsigned short u16x4 __attribute__((ext_vector_type(4)));

static constexpr int B_ = 2, N_ = 2048, DIM_ = 256, H_ = 4, DH_ = 32;
static constexpr int NQKV_ = 3 * H_ * DH_;  // 384
static constexpr float SCALE_ = 0.17677669529663687f;  // DH^-0.5

DEVI unsigned short f2bf(float f) {
  __hip_bfloat16 h = __float2bfloat16(f);
  return *reinterpret_cast<unsigned short*>(&h);
}

// --------------------------------------------------------------- qkv gemm ---
// Identical to round 10 except the W-staging loop is BATCHED: 8 loads issued
// back-to-back into registers (no intervening uses -> all in flight), then
// convert+store. Same elements, same destinations, same numerics.
__global__ __launch_bounds__(256) void k_gemm_qkv(
    const float* __restrict__ X,            // x fp32 [4096][256]
    const float* __restrict__ Wqkv,         // fp32 [256][384]
    unsigned short* __restrict__ Qo,        // [B,H,N,DH] pre-scaled
    unsigned short* __restrict__ Ko,        // [B,H,N,DH]
    unsigned short* __restrict__ Vo,        // [B,H,N,DH]
    unsigned short* __restrict__ Vto) {     // [B,H,DH,N] key-permuted
  constexpr int LDB = 258;                  // halves
  __shared__ unsigned short Bts[64 * LDB];  // 32.25 KB
  const int tid = threadIdx.x;
  const int col0b = blockIdx.y * 64;
  // ---- stage W slice, batched (col = tid&63 fixed; k walks tid>>6 + 4i)
  {
    const int col = tid & 63;
    const int k0 = tid >> 6;
    const float* src = Wqkv + col0b + col;
#pragma unroll
    for (int gb = 0; gb < 8; gb++) {
      float v[8];
#pragma unroll
      for (int j = 0; j < 8; j++)
        v[j] = src[(size_t)(k0 + (gb * 8 + j) * 4) * NQKV_];
#pragma unroll
      for (int j = 0; j < 8; j++)
        Bts[col * LDB + k0 + (gb * 8 + j) * 4] = f2bf(v[j]);
    }
  }
  __syncthreads();

  const int w = tid >> 6, l = tid & 63;
  const int lr = l & 15, g = l >> 4;
  const int row0 = blockIdx.x * 64 + (w >> 1) * 32;
  const int colw = (w & 1) * 32;
  const float* xr0 = X + (size_t)(row0 + lr) * 256;
  const float* xr1 = X + (size_t)(row0 + 16 + lr) * 256;
  f32x4 acc[2][2] = {};
#pragma unroll
  for (int kb = 0; kb < 256; kb += 32) {
    f32x4 xa = *(const f32x4*)(xr0 + kb + g * 8);
    f32x4 xb4 = *(const f32x4*)(xr0 + kb + g * 8 + 4);
    f32x4 xc = *(const f32x4*)(xr1 + kb + g * 8);
    f32x4 xd = *(const f32x4*)(xr1 + kb + g * 8 + 4);
    bf16x8 a0, a1;
#pragma unroll
    for (int j = 0; j < 4; j++) {
      a0[j] = (short)f2bf(xa[j]);
      a0[4 + j] = (short)f2bf(xb4[j]);
      a1[j] = (short)f2bf(xc[j]);
      a1[4 + j] = (short)f2bf(xd[j]);
    }
    bf16x8 b0 = *(const bf16x8*)(&Bts[(colw + lr) * LDB + kb + g * 8]);
    bf16x8 b1 = *(const bf16x8*)(&Bts[(colw + 16 + lr) * LDB + kb + g * 8]);
    acc[0][0] = __builtin_amdgcn_mfma_f32_16x16x32_bf16(a0, b0, acc[0][0], 0, 0, 0);
    acc[0][1] = __builtin_amdgcn_mfma_f32_16x16x32_bf16(a0, b1, acc[0][1], 0, 0, 0);
    acc[1][0] = __builtin_amdgcn_mfma_f32_16x16x32_bf16(a1, b0, acc[1][0], 0, 0, 0);
    acc[1][1] = __builtin_amdgcn_mfma_f32_16x16x32_bf16(a1, b1, acc[1][1], 0, 0, 0);
  }
#pragma unroll
  for (int mi = 0; mi < 2; mi++)
#pragma unroll
    for (int ni = 0; ni < 2; ni++) {
      const int colg = col0b + colw + ni * 16 + lr;  // 0..383
      const int sec = colg >> 7;                     // 0=Q 1=K 2=V
      const int h = (colg >> 5) & 3;
      const int d = colg & 31;
      const int rbase = row0 + mi * 16 + g * 4;
      const int bb = rbase >> 11;
      const int n0 = rbase & (N_ - 1);
      if (sec == 0) {
#pragma unroll
        for (int r = 0; r < 4; r++)
          Qo[((bb * H_ + h) * N_ + n0 + r) * DH_ + d] = f2bf(acc[mi][ni][r] * SCALE_);
      } else if (sec == 1) {
#pragma unroll
        for (int r = 0; r < 4; r++)
          Ko[((bb * H_ + h) * N_ + n0 + r) * DH_ + d] = f2bf(acc[mi][ni][r]);
      } else {
        u16x4 vp;
#pragma unroll
        for (int r = 0; r < 4; r++) {
          const unsigned short vb = f2bf(acc[mi][ni][r]);
          Vo[((bb * H_ + h) * N_ + n0 + r) * DH_ + d] = vb;
          vp[r] = vb;
        }
        // key-permuted Vt: slot s holds key(s)=4*(s>>3)+(s&3)+16*((s>>2)&1)
        const int c32 = n0 & ~31;
        const int local = n0 & 31;
        const int slot = ((local & 15) >> 2) * 8 + ((local >> 4) << 2);
        *(u16x4*)(Vto + ((bb * H_ + h) * DH_ + d) * N_ + c32 + slot) = vp;
      }
    }
}

// ---------------- attention (LDS split-K + coalesced bias staging) ----------
// (byte-identical to round 10 — the proven 41.6 µs structure)
__global__ __launch_bounds__(512) void k_attn_lds(
    const unsigned short* __restrict__ Q,
    const unsigned short* __restrict__ K,
    const unsigned short* __restrict__ Vt,
    const unsigned short* __restrict__ V,
    const float* __restrict__ bias,
    const int* __restrict__ mask,
    unsigned short* __restrict__ AO) {      // [B*N][128] bf16
  const int bh = blockIdx.y;
  const int b = bh >> 2, h = bh & 3;
  const int qt = blockIdx.x;                // 0..127 (16 q-rows each)
  const int tid = threadIdx.x;
  const int qb = qt * 16;
  if (mask[b] != 0) {
    if (tid < 64) {
      const int q = tid >> 2;
      const int d8 = (tid & 3) * 8;
      bf16x8 v = *(const bf16x8*)(V + ((size_t)bh * N_ + qb + q) * DH_ + d8);
      *(bf16x8*)(AO + (size_t)(b * N_ + qb + q) * (H_ * DH_) + h * DH_ + d8) = v;
    }
    return;
  }
  constexpr int LDBS = 258;            // f32 stride: ~2-way bank alias (free)
  __shared__ float so[16][8][32];      // 16 KB
  __shared__ float ss[16][8];          // 512 B
  __shared__ float bs[2][16][LDBS];    // 33 KB bias double buffer
  const int w = tid >> 6, l = tid & 63, lr = l & 15, g = l >> 4;
  const int srow = tid >> 5;           // 0..15
  const int sidx = tid & 31;           // 0..31
  const float* brow_g = bias + (size_t)(h * N_ + qb + srow) * N_;
  const unsigned short* Kp = K + bh * N_ * DH_;
  const unsigned short* Vtp = Vt + bh * DH_ * N_;
  const bf16x8 qf = *(const bf16x8*)(Q + (bh * N_ + qb + lr) * DH_ + g * 8);
  // prologue: stage chunk 0
  {
    f32x4 p0 = *(const f32x4*)(brow_g + sidx * 4);
    f32x4 p1 = *(const f32x4*)(brow_g + 128 + sidx * 4);
    *(f32x4*)&bs[0][srow][sidx * 4] = p0;
    *(f32x4*)&bs[0][srow][128 + sidx * 4] = p1;
  }
  __syncthreads();
  float s = 0.f;
  f32x4 o0 = {}, o1 = {};
  int cur = 0;
#pragma unroll
  for (int ci = 0; ci < 8; ci++) {
    // prefetch next chunk's bias into registers (HBM latency hides under body)
    f32x4 n0 = {}, n1 = {};
    if (ci < 7) {
      n0 = *(const f32x4*)(brow_g + (ci + 1) * 256 + sidx * 4);
      n1 = *(const f32x4*)(brow_g + (ci + 1) * 256 + 128 + sidx * 4);
    }
    // ---- 32-key body at c = ci*256 + w*32, bias from LDS
    {
      const int c = ci * 256 + w * 32;
      bf16x8 k0 = *(const bf16x8*)(Kp + (c + lr) * DH_ + g * 8);
      bf16x8 k1 = *(const bf16x8*)(Kp + (c + 16 + lr) * DH_ + g * 8);
      f32x4 z = {};
      f32x4 st0 = __builtin_amdgcn_mfma_f32_16x16x32_bf16(k0, qf, z, 0, 0, 0);
      f32x4 st1 = __builtin_amdgcn_mfma_f32_16x16x32_bf16(k1, qf, z, 0, 0, 0);
      f32x4 bi0 = *(const f32x4*)(&bs[cur][lr][w * 32 + g * 4]);
      f32x4 bi1 = *(const f32x4*)(&bs[cur][lr][w * 32 + 16 + g * 4]);
      bf16x8 pf;
#pragma unroll
      for (int r = 0; r < 4; r++) {
        const float p0 = __expf(st0[r] + bi0[r]);
        const float p1 = __expf(st1[r] + bi1[r]);
        s += p0 + p1;
        pf[r] = (short)f2bf(p0);
        pf[4 + r] = (short)f2bf(p1);
      }
      bf16x8 v0 = *(const bf16x8*)(Vtp + lr * N_ + c + g * 8);
      bf16x8 v1 = *(const bf16x8*)(Vtp + (16 + lr) * N_ + c + g * 8);
      o0 = __builtin_amdgcn_mfma_f32_16x16x32_bf16(v0, pf, o0, 0, 0, 0);
      o1 = __builtin_amdgcn_mfma_f32_16x16x32_bf16(v1, pf, o1, 0, 0, 0);
    }
    __syncthreads();  // all reads of bs[cur^1] (prev iter) and bs[cur] done
    if (ci < 7) {
      *(f32x4*)&bs[cur ^ 1][srow][sidx * 4] = n0;
      *(f32x4*)&bs[cur ^ 1][srow][128 + sidx * 4] = n1;
    }
    __syncthreads();  // next-chunk bias visible
    cur ^= 1;
  }
  // per-wave s for q=lr: reduce over the 4 lane-groups
  s += __shfl_xor(s, 16);
  s += __shfl_xor(s, 32);
  *(f32x4*)&so[lr][w][g * 4] = o0;
  *(f32x4*)&so[lr][w][16 + g * 4] = o1;
  if (g == 0) ss[lr][w] = s;
  __syncthreads();
  // cross-wave reduce + normalize + AO write: thread t -> q=t>>5, d=t&31
  {
    const int q = tid >> 5;
    const int d = tid & 31;
    float acc = 0.f, ssum = 0.f;
#pragma unroll
    for (int w2 = 0; w2 < 8; w2++) {
      acc += so[q][w2][d];
      ssum += ss[q][w2];
    }
    AO[(size_t)(b * N_ + qb + q) * (H_ * DH_) + h * DH_ + d] = f2bf(acc / ssum);
  }
}

// --------------------------------------------------------------- out gemm ---
// Identical to round 10 except batched W-staging (4 groups of 8 loads).
__global__ __launch_bounds__(256) void k_gemm_out(
    const unsigned short* __restrict__ A,   // AO [4096][128]
    const float* __restrict__ Wout,         // fp32 [128][256]
    float* __restrict__ out) {              // [4096][256] fp32
  constexpr int LDB = 130;                  // halves
  __shared__ unsigned short Bts[64 * LDB];  // 16.25 KB
  const int tid = threadIdx.x;
  const int col0b = blockIdx.y * 64;
  {
    const int col = tid & 63;
    const int k0 = tid >> 6;
    const float* src = Wout + col0b + col;
#pragma unroll
    for (int gb = 0; gb < 4; gb++) {
      float v[8];
#pragma unroll
      for (int j = 0; j < 8; j++)
        v[j] = src[(size_t)(k0 + (gb * 8 + j) * 4) * 256];
#pragma unroll
      for (int j = 0; j < 8; j++)
        Bts[col * LDB + k0 + (gb * 8 + j) * 4] = f2bf(v[j]);
    }
  }
  __syncthreads();

  const int w = tid >> 6, l = tid & 63;
  const int lr = l & 15, g = l >> 4;
  const int row0 = blockIdx.x * 64 + (w >> 1) * 32;
  const int colw = (w & 1) * 32;
  f32x4 acc[2][2] = {};
#pragma unroll
  for (int kb = 0; kb < 128; kb += 32) {
    bf16x8 a0 = *(const bf16x8*)(A + (row0 + lr) * 128 + kb + g * 8);
    bf16x8 a1 = *(const bf16x8*)(A + (row0 + 16 + lr) * 128 + kb + g * 8);
    bf16x8 b0 = *(const bf16x8*)(&Bts[(colw + lr) * LDB + kb + g * 8]);
    bf16x8 b1 = *(const bf16x8*)(&Bts[(colw + 16 + lr) * LDB + kb + g * 8]);
    acc[0][0] = __builtin_amdgcn_mfma_f32_16x16x32_bf16(a0, b0, acc[0][0], 0, 0, 0);
    acc[0][1] = __builtin_amdgcn_mfma_f32_16x16x32_bf16(a0, b1, acc[0][1], 0, 0, 0);
    acc[1][0] = __builtin_amdgcn_mfma_f32_16x16x32_bf16(a1, b0, acc[1][0], 0, 0, 0);
    acc[1][1] = __builtin_amdgcn_mfma_f32_16x16x32_bf16(a1, b1, acc[1][1], 0, 0, 0);
  }
#pragma unroll
  for (int mi = 0; mi < 2; mi++)
#pragma unroll
    for (int ni = 0; ni < 2; ni++) {
      const int colg = col0b + colw + ni * 16 + lr;
      const int rbase = row0 + mi * 16 + g * 4;
#pragma unroll
      for (int r = 0; r < 4; r++)
        out[(size_t)(rbase + r) * 256 + colg] = acc[mi][ni][r];
    }
}

// ------------------------------------------------------------------ launch ---
extern "C" void kernel_launch(void* const* d_in, const int* in_sizes, int n_in,
                              void* d_out, int out_size, void* d_ws, size_t ws_size,
                              hipStream_t stream) {
  const float* x = (const float*)d_in[0];
  const float* bias = (const float*)d_in[1];
  const int* mask = (const int*)d_in[2];
  const float* Wqkv = (const float*)d_in[3];
  const float* Wout = (const float*)d_in[4];
  float* out = (float*)d_out;
  char* ws = (char*)d_ws;

  unsigned short* Qb  = (unsigned short*)(ws + 0);         // 1 MB
  unsigned short* Kb  = (unsigned short*)(ws + 1048576);   // 1 MB
  unsigned short* Vb  = (unsigned short*)(ws + 2097152);   // 1 MB
  unsigned short* Vtb = (unsigned short*)(ws + 3145728);   // 1 MB
  unsigned short* AOb = (unsigned short*)(ws + 4194304);   // 1 MB

  k_gemm_qkv<<<dim3(64, 6), dim3(256), 0, stream>>>(x, Wqkv, Qb, Kb, Vb, Vtb);
  k_attn_lds<<<dim3(128, B_ * H_), dim3(512), 0, stream>>>(
      Qb, Kb, Vtb, Vb, bias, mask, AOb);
  k_gemm_out<<<dim3(64, 4), dim3(256), 0, stream>>>(AOb, Wout, out);
}

// Round 19
// 38.366 us; speedup vs baseline: 1.2944x; 1.0057x over previous
//
#include <hip/hip_runtime.h>
#include <hip/hip_bf16.h>

#define DEVI __device__ __forceinline__

typedef short bf16x8 __attribute__((ext_vector_type(8)));
typedef float f32x4 __attribute__((ext_vector_type(4)));
typedef unsigned short u16x4 __attribute__((ext_vector_type(4)));

static constexpr int B_ = 2, N_ = 2048, DIM_ = 256, H_ = 4, DH_ = 32;
static constexpr int NQKV_ = 3 * H_ * DH_;  // 384
static constexpr float SCALE_ = 0.17677669529663687f;  // DH^-0.5

DEVI unsigned short f2bf(float f) {
  __hip_bfloat16 h = __float2bfloat16(f);
  return *reinterpret_cast<unsigned short*>(&h);
}

// --------------------------------------------------------------- qkv gemm ---
// Identical to round 10 except the W-staging loop is BATCHED: 8 loads issued
// back-to-back into registers (no intervening uses -> all in flight), then
// convert+store. Same elements, same destinations, same numerics.
__global__ __launch_bounds__(256) void k_gemm_qkv(
    const float* __restrict__ X,            // x fp32 [4096][256]
    const float* __restrict__ Wqkv,         // fp32 [256][384]
    unsigned short* __restrict__ Qo,        // [B,H,N,DH] pre-scaled
    unsigned short* __restrict__ Ko,        // [B,H,N,DH]
    unsigned short* __restrict__ Vo,        // [B,H,N,DH]
    unsigned short* __restrict__ Vto) {     // [B,H,DH,N] key-permuted
  constexpr int LDB = 258;                  // halves
  __shared__ unsigned short Bts[64 * LDB];  // 32.25 KB
  const int tid = threadIdx.x;
  const int col0b = blockIdx.y * 64;
  // ---- stage W slice, batched (col = tid&63 fixed; k walks tid>>6 + 4i)
  {
    const int col = tid & 63;
    const int k0 = tid >> 6;
    const float* src = Wqkv + col0b + col;
#pragma unroll
    for (int gb = 0; gb < 8; gb++) {
      float v[8];
#pragma unroll
      for (int j = 0; j < 8; j++)
        v[j] = src[(size_t)(k0 + (gb * 8 + j) * 4) * NQKV_];
#pragma unroll
      for (int j = 0; j < 8; j++)
        Bts[col * LDB + k0 + (gb * 8 + j) * 4] = f2bf(v[j]);
    }
  }
  __syncthreads();

  const int w = tid >> 6, l = tid & 63;
  const int lr = l & 15, g = l >> 4;
  const int row0 = blockIdx.x * 64 + (w >> 1) * 32;
  const int colw = (w & 1) * 32;
  const float* xr0 = X + (size_t)(row0 + lr) * 256;
  const float* xr1 = X + (size_t)(row0 + 16 + lr) * 256;
  f32x4 acc[2][2] = {};
#pragma unroll
  for (int kb = 0; kb < 256; kb += 32) {
    f32x4 xa = *(const f32x4*)(xr0 + kb + g * 8);
    f32x4 xb4 = *(const f32x4*)(xr0 + kb + g * 8 + 4);
    f32x4 xc = *(const f32x4*)(xr1 + kb + g * 8);
    f32x4 xd = *(const f32x4*)(xr1 + kb + g * 8 + 4);
    bf16x8 a0, a1;
#pragma unroll
    for (int j = 0; j < 4; j++) {
      a0[j] = (short)f2bf(xa[j]);
      a0[4 + j] = (short)f2bf(xb4[j]);
      a1[j] = (short)f2bf(xc[j]);
      a1[4 + j] = (short)f2bf(xd[j]);
    }
    bf16x8 b0 = *(const bf16x8*)(&Bts[(colw + lr) * LDB + kb + g * 8]);
    bf16x8 b1 = *(const bf16x8*)(&Bts[(colw + 16 + lr) * LDB + kb + g * 8]);
    acc[0][0] = __builtin_amdgcn_mfma_f32_16x16x32_bf16(a0, b0, acc[0][0], 0, 0, 0);
    acc[0][1] = __builtin_amdgcn_mfma_f32_16x16x32_bf16(a0, b1, acc[0][1], 0, 0, 0);
    acc[1][0] = __builtin_amdgcn_mfma_f32_16x16x32_bf16(a1, b0, acc[1][0], 0, 0, 0);
    acc[1][1] = __builtin_amdgcn_mfma_f32_16x16x32_bf16(a1, b1, acc[1][1], 0, 0, 0);
  }
#pragma unroll
  for (int mi = 0; mi < 2; mi++)
#pragma unroll
    for (int ni = 0; ni < 2; ni++) {
      const int colg = col0b + colw + ni * 16 + lr;  // 0..383
      const int sec = colg >> 7;                     // 0=Q 1=K 2=V
      const int h = (colg >> 5) & 3;
      const int d = colg & 31;
      const int rbase = row0 + mi * 16 + g * 4;
      const int bb = rbase >> 11;
      const int n0 = rbase & (N_ - 1);
      if (sec == 0) {
#pragma unroll
        for (int r = 0; r < 4; r++)
          Qo[((bb * H_ + h) * N_ + n0 + r) * DH_ + d] = f2bf(acc[mi][ni][r] * SCALE_);
      } else if (sec == 1) {
#pragma unroll
        for (int r = 0; r < 4; r++)
          Ko[((bb * H_ + h) * N_ + n0 + r) * DH_ + d] = f2bf(acc[mi][ni][r]);
      } else {
        u16x4 vp;
#pragma unroll
        for (int r = 0; r < 4; r++) {
          const unsigned short vb = f2bf(acc[mi][ni][r]);
          Vo[((bb * H_ + h) * N_ + n0 + r) * DH_ + d] = vb;
          vp[r] = vb;
        }
        // key-permuted Vt: slot s holds key(s)=4*(s>>3)+(s&3)+16*((s>>2)&1)
        const int c32 = n0 & ~31;
        const int local = n0 & 31;
        const int slot = ((local & 15) >> 2) * 8 + ((local >> 4) << 2);
        *(u16x4*)(Vto + ((bb * H_ + h) * DH_ + d) * N_ + c32 + slot) = vp;
      }
    }
}

// ---------------- attention (LDS split-K + coalesced bias staging) ----------
// (byte-identical to round 10 — the proven 41.6 µs structure)
__global__ __launch_bounds__(512) void k_attn_lds(
    const unsigned short* __restrict__ Q,
    const unsigned short* __restrict__ K,
    const unsigned short* __restrict__ Vt,
    const unsigned short* __restrict__ V,
    const float* __restrict__ bias,
    const int* __restrict__ mask,
    unsigned short* __restrict__ AO) {      // [B*N][128] bf16
  const int bh = blockIdx.y;
  const int b = bh >> 2, h = bh & 3;
  const int qt = blockIdx.x;                // 0..127 (16 q-rows each)
  const int tid = threadIdx.x;
  const int qb = qt * 16;
  if (mask[b] != 0) {
    if (tid < 64) {
      const int q = tid >> 2;
      const int d8 = (tid & 3) * 8;
      bf16x8 v = *(const bf16x8*)(V + ((size_t)bh * N_ + qb + q) * DH_ + d8);
      *(bf16x8*)(AO + (size_t)(b * N_ + qb + q) * (H_ * DH_) + h * DH_ + d8) = v;
    }
    return;
  }
  constexpr int LDBS = 258;            // f32 stride: ~2-way bank alias (free)
  __shared__ float so[16][8][32];      // 16 KB
  __shared__ float ss[16][8];          // 512 B
  __shared__ float bs[2][16][LDBS];    // 33 KB bias double buffer
  const int w = tid >> 6, l = tid & 63, lr = l & 15, g = l >> 4;
  const int srow = tid >> 5;           // 0..15
  const int sidx = tid & 31;           // 0..31
  const float* brow_g = bias + (size_t)(h * N_ + qb + srow) * N_;
  const unsigned short* Kp = K + bh * N_ * DH_;
  const unsigned short* Vtp = Vt + bh * DH_ * N_;
  const bf16x8 qf = *(const bf16x8*)(Q + (bh * N_ + qb + lr) * DH_ + g * 8);
  // prologue: stage chunk 0
  {
    f32x4 p0 = *(const f32x4*)(brow_g + sidx * 4);
    f32x4 p1 = *(const f32x4*)(brow_g + 128 + sidx * 4);
    *(f32x4*)&bs[0][srow][sidx * 4] = p0;
    *(f32x4*)&bs[0][srow][128 + sidx * 4] = p1;
  }
  __syncthreads();
  float s = 0.f;
  f32x4 o0 = {}, o1 = {};
  int cur = 0;
#pragma unroll
  for (int ci = 0; ci < 8; ci++) {
    // prefetch next chunk's bias into registers (HBM latency hides under body)
    f32x4 n0 = {}, n1 = {};
    if (ci < 7) {
      n0 = *(const f32x4*)(brow_g + (ci + 1) * 256 + sidx * 4);
      n1 = *(const f32x4*)(brow_g + (ci + 1) * 256 + 128 + sidx * 4);
    }
    // ---- 32-key body at c = ci*256 + w*32, bias from LDS
    {
      const int c = ci * 256 + w * 32;
      bf16x8 k0 = *(const bf16x8*)(Kp + (c + lr) * DH_ + g * 8);
      bf16x8 k1 = *(const bf16x8*)(Kp + (c + 16 + lr) * DH_ + g * 8);
      f32x4 z = {};
      f32x4 st0 = __builtin_amdgcn_mfma_f32_16x16x32_bf16(k0, qf, z, 0, 0, 0);
      f32x4 st1 = __builtin_amdgcn_mfma_f32_16x16x32_bf16(k1, qf, z, 0, 0, 0);
      f32x4 bi0 = *(const f32x4*)(&bs[cur][lr][w * 32 + g * 4]);
      f32x4 bi1 = *(const f32x4*)(&bs[cur][lr][w * 32 + 16 + g * 4]);
      bf16x8 pf;
#pragma unroll
      for (int r = 0; r < 4; r++) {
        const float p0 = __expf(st0[r] + bi0[r]);
        const float p1 = __expf(st1[r] + bi1[r]);
        s += p0 + p1;
        pf[r] = (short)f2bf(p0);
        pf[4 + r] = (short)f2bf(p1);
      }
      bf16x8 v0 = *(const bf16x8*)(Vtp + lr * N_ + c + g * 8);
      bf16x8 v1 = *(const bf16x8*)(Vtp + (16 + lr) * N_ + c + g * 8);
      o0 = __builtin_amdgcn_mfma_f32_16x16x32_bf16(v0, pf, o0, 0, 0, 0);
      o1 = __builtin_amdgcn_mfma_f32_16x16x32_bf16(v1, pf, o1, 0, 0, 0);
    }
    __syncthreads();  // all reads of bs[cur^1] (prev iter) and bs[cur] done
    if (ci < 7) {
      *(f32x4*)&bs[cur ^ 1][srow][sidx * 4] = n0;
      *(f32x4*)&bs[cur ^ 1][srow][128 + sidx * 4] = n1;
    }
    __syncthreads();  // next-chunk bias visible
    cur ^= 1;
  }
  // per-wave s for q=lr: reduce over the 4 lane-groups
  s += __shfl_xor(s, 16);
  s += __shfl_xor(s, 32);
  *(f32x4*)&so[lr][w][g * 4] = o0;
  *(f32x4*)&so[lr][w][16 + g * 4] = o1;
  if (g == 0) ss[lr][w] = s;
  __syncthreads();
  // cross-wave reduce + normalize + AO write: thread t -> q=t>>5, d=t&31
  {
    const int q = tid >> 5;
    const int d = tid & 31;
    float acc = 0.f, ssum = 0.f;
#pragma unroll
    for (int w2 = 0; w2 < 8; w2++) {
      acc += so[q][w2][d];
      ssum += ss[q][w2];
    }
    AO[(size_t)(b * N_ + qb + q) * (H_ * DH_) + h * DH_ + d] = f2bf(acc / ssum);
  }
}

// --------------------------------------------------------------- out gemm ---
// Identical to round 10 except batched W-staging (4 groups of 8 loads).
__global__ __launch_bounds__(256) void k_gemm_out(
    const unsigned short* __restrict__ A,   // AO [4096][128]
    const float* __restrict__ Wout,         // fp32 [128][256]
    float* __restrict__ out) {              // [4096][256] fp32
  constexpr int LDB = 130;                  // halves
  __shared__ unsigned short Bts[64 * LDB];  // 16.25 KB
  const int tid = threadIdx.x;
  const int col0b = blockIdx.y * 64;
  {
    const int col = tid & 63;
    const int k0 = tid >> 6;
    const float* src = Wout + col0b + col;
#pragma unroll
    for (int gb = 0; gb < 4; gb++) {
      float v[8];
#pragma unroll
      for (int j = 0; j < 8; j++)
        v[j] = src[(size_t)(k0 + (gb * 8 + j) * 4) * 256];
#pragma unroll
      for (int j = 0; j < 8; j++)
        Bts[col * LDB + k0 + (gb * 8 + j) * 4] = f2bf(v[j]);
    }
  }
  __syncthreads();

  const int w = tid >> 6, l = tid & 63;
  const int lr = l & 15, g = l >> 4;
  const int row0 = blockIdx.x * 64 + (w >> 1) * 32;
  const int colw = (w & 1) * 32;
  f32x4 acc[2][2] = {};
#pragma unroll
  for (int kb = 0; kb < 128; kb += 32) {
    bf16x8 a0 = *(const bf16x8*)(A + (row0 + lr) * 128 + kb + g * 8);
    bf16x8 a1 = *(const bf16x8*)(A + (row0 + 16 + lr) * 128 + kb + g * 8);
    bf16x8 b0 = *(const bf16x8*)(&Bts[(colw + lr) * LDB + kb + g * 8]);
    bf16x8 b1 = *(const bf16x8*)(&Bts[(colw + 16 + lr) * LDB + kb + g * 8]);
    acc[0][0] = __builtin_amdgcn_mfma_f32_16x16x32_bf16(a0, b0, acc[0][0], 0, 0, 0);
    acc[0][1] = __builtin_amdgcn_mfma_f32_16x16x32_bf16(a0, b1, acc[0][1], 0, 0, 0);
    acc[1][0] = __builtin_amdgcn_mfma_f32_16x16x32_bf16(a1, b0, acc[1][0], 0, 0, 0);
    acc[1][1] = __builtin_amdgcn_mfma_f32_16x16x32_bf16(a1, b1, acc[1][1], 0, 0, 0);
  }
#pragma unroll
  for (int mi = 0; mi < 2; mi++)
#pragma unroll
    for (int ni = 0; ni < 2; ni++) {
      const int colg = col0b + colw + ni * 16 + lr;
      const int rbase = row0 + mi * 16 + g * 4;
#pragma unroll
      for (int r = 0; r < 4; r++)
        out[(size_t)(rbase + r) * 256 + colg] = acc[mi][ni][r];
    }
}

// ------------------------------------------------------------------ launch ---
extern "C" void kernel_launch(void* const* d_in, const int* in_sizes, int n_in,
                              void* d_out, int out_size, void* d_ws, size_t ws_size,
                              hipStream_t stream) {
  const float* x = (const float*)d_in[0];
  const float* bias = (const float*)d_in[1];
  const int* mask = (const int*)d_in[2];
  const float* Wqkv = (const float*)d_in[3];
  const float* Wout = (const float*)d_in[4];
  float* out = (float*)d_out;
  char* ws = (char*)d_ws;

  unsigned short* Qb  = (unsigned short*)(ws + 0);         // 1 MB
  unsigned short* Kb  = (unsigned short*)(ws + 1048576);   // 1 MB
  unsigned short* Vb  = (unsigned short*)(ws + 2097152);   // 1 MB
  unsigned short* Vtb = (unsigned short*)(ws + 3145728);   // 1 MB
  unsigned short* AOb = (unsigned short*)(ws + 4194304);   // 1 MB

  k_gemm_qkv<<<dim3(64, 6), dim3(256), 0, stream>>>(x, Wqkv, Qb, Kb, Vb, Vtb);
  k_attn_lds<<<dim3(128, B_ * H_), dim3(512), 0, stream>>>(
      Qb, Kb, Vtb, Vb, bias, mask, AOb);
  k_gemm_out<<<dim3(64, 4), dim3(256), 0, stream>>>(AOb, Wout, out);
}